// Round 6
// baseline (703.986 us; speedup 1.0000x reference)
//
#include <hip/hip_runtime.h>
#include <hip/hip_bf16.h>
#include <math.h>

// Pipeline:
//  K0 cvt       : wq -> bf16 FRAGMENT-ORDER; wout -> bf16 linear;
//                 conv_w [o][i][k] -> 3x bf16 W_k[o][i]
//  K1a pat_ln   : pat2 = LN(LN(pattern)) fp32                         -> pat2
//                 (pat2 ALIASES the head of ao_bf: live ranges disjoint —
//                  pat2 dead after K1b; ao_bf written first by K3)
//  K1b kv_frag  : kv = pat2 @ wkv^T, grid (kt=16, h=8); each block owns the
//                 CONTIGUOUS 2KB fragment-order regions k_bf[h][kt] and
//                 v_t[h][kt] -> coalesced 16B stores (fixes r4's 450x write
//                 amplification from cross-block single-short scatter)
//  K2 conv_ln   : y = sum_k Xshift_k @ W_k^T (MFMA) + b + x, leaky, LN -> xn_bf
//  K3 qattn     : FUSED q-proj + S^T-orientation MFMA attention       -> ao_bf
//                 NO LDS, NO barriers. 64 queries/wave (4 groups of 16).
//                 All K/V/wq fragment loads lane-linear (frag-order layout).
//  K4 outproj_ln: ao @ wout^T (MFMA) + bout, LN                       -> d_out
//
// T=65536, D=256, P=512, H=8, dA=64, seqlen=2048.
// perm32(c) permutes bits 2..4: (b4,b3,b2)->(b2,b4,b3); inv32 is its inverse
// (3-cycle: inv32^-1(c) = (c&~0x1C)|((c&0x18)>>1)|((c&4)<<2)).
// Fragment-order for a 16-row x 32-col bf16 MFMA A-frag batch: element
// (row=cl, col=g*8+e) of sub-frag f lives at f*512 + (cl+16*g)*8 + e, so the
// consuming wave (lane = cl+16g) loads s16x8 at base + lane*8: contiguous.
//
// Workspace high-water mark kept at the round-4-proven 102,629,376 bytes
// (round 5's container fault was consistent with pat2 extending past ws_size).

#define EPSF 1e-5f

typedef short  s16x8 __attribute__((ext_vector_type(8)));
typedef short  s16x4 __attribute__((ext_vector_type(4)));
typedef float  f32x4 __attribute__((ext_vector_type(4)));

__device__ __forceinline__ unsigned short f2bf(float f) {
    union { float f; unsigned u; } v; v.f = f;
    unsigned r = (v.u + 0x7fffu + ((v.u >> 16) & 1u)) >> 16;   // RNE
    return (unsigned short)r;
}
__device__ __forceinline__ float bf2f(unsigned short h) {
    union { unsigned u; float f; } v; v.u = ((unsigned)h) << 16;
    return v.f;
}
__device__ __forceinline__ unsigned fbits(float f) {
    union { float f; unsigned u; } v; v.f = f; return v.u;
}
// pack two floats' high halves (truncate-to-bf16): low16 = lo, high16 = hi
__device__ __forceinline__ unsigned pk_hi(float lo, float hi) {
    return __builtin_amdgcn_perm(fbits(hi), fbits(lo), 0x07060302u);
}
__device__ __forceinline__ int inv32(int t) {   // inverse of perm32, touches bits 2..4
    return (t & ~31) | ((t & 0x0C) << 1) | ((t & 0x10) >> 2) | (t & 3);
}

union Bfrag { unsigned u[4]; s16x8 s; };

// ---------------------------------------------------------------- K0
__global__ void cvt_kernel(const float* __restrict__ wq,
                           const float* __restrict__ wout,
                           const float* __restrict__ cw,
                           short* __restrict__ wq_bf,     // fragment-order
                           short* __restrict__ wout_bf,   // linear
                           short* __restrict__ wck) {
    const int b = blockIdx.x, tid = threadIdx.x;
    if (b < 128) {
        // wq [512][256] -> fragment order
        const int i = (b * 256 + tid) * 4;
        const int R = i >> 8, C = i & 255;
        const float4 x = *(const float4*)(wq + i);
        s16x4 o; o[0] = f2bf(x.x); o[1] = f2bf(x.y); o[2] = f2bf(x.z); o[3] = f2bf(x.w);
        const int off = ((R >> 6) * 32 + ((R >> 4) & 3) * 8 + (C >> 5)) * 512
                      + ((R & 15) + ((C >> 3) & 3) * 16) * 8 + (C & 7);
        *(s16x4*)(wq_bf + off) = o;
    } else if (b < 256) {
        const int i = ((b - 128) * 256 + tid) * 4;
        const float4 x = *(const float4*)(wout + i);
        s16x4 o; o[0] = f2bf(x.x); o[1] = f2bf(x.y); o[2] = f2bf(x.z); o[3] = f2bf(x.w);
        *(s16x4*)(wout_bf + i) = o;
    } else {
        const int idx = (b - 256) * 256 + tid;          // (o,i) pair, 65536 total
        const float* p = cw + (size_t)idx * 3;
        wck[idx]              = (short)f2bf(p[0]);
        wck[65536 + idx]      = (short)f2bf(p[1]);
        wck[131072 + idx]     = (short)f2bf(p[2]);
    }
}

// ---------------------------------------------------------------- K1a: LN(LN(pattern)) -> pat2 fp32
__global__ void pat_ln_kernel(const float* __restrict__ pattern,
                              float* __restrict__ pat2) {
    __shared__ float scr[4];
    const int w = blockIdx.x;
    const int tid = threadIdx.x;
    const int lane = tid & 63, wav = tid >> 6;

    float v = pattern[(size_t)w * 256 + tid];

    float s = v;
    #pragma unroll
    for (int off = 32; off; off >>= 1) s += __shfl_xor(s, off);
    if (lane == 0) scr[wav] = s;
    __syncthreads();
    float mu = (scr[0] + scr[1] + scr[2] + scr[3]) * (1.f / 256.f);
    __syncthreads();
    float d = v - mu;
    float s2 = d * d;
    #pragma unroll
    for (int off = 32; off; off >>= 1) s2 += __shfl_xor(s2, off);
    if (lane == 0) scr[wav] = s2;
    __syncthreads();
    float var = (scr[0] + scr[1] + scr[2] + scr[3]) * (1.f / 256.f);
    float x1 = d * rsqrtf(var + EPSF);
    __syncthreads();

    s = x1;
    #pragma unroll
    for (int off = 32; off; off >>= 1) s += __shfl_xor(s, off);
    if (lane == 0) scr[wav] = s;
    __syncthreads();
    mu = (scr[0] + scr[1] + scr[2] + scr[3]) * (1.f / 256.f);
    __syncthreads();
    d = x1 - mu;
    s2 = d * d;
    #pragma unroll
    for (int off = 32; off; off >>= 1) s2 += __shfl_xor(s2, off);
    if (lane == 0) scr[wav] = s2;
    __syncthreads();
    var = (scr[0] + scr[1] + scr[2] + scr[3]) * (1.f / 256.f);
    pat2[(size_t)w * 256 + tid] = d * rsqrtf(var + EPSF);
}

// ---------------------------------------------------------------- K1b: kv GEMM -> fragment-order, coalesced
// Grid (kt=16, h=8), 256 threads. Block computes patterns [kt*32, +32) x
// wkv rows [h*128, +128), stages 32x128 fp32 in LDS, then writes the
// contiguous 2KB-short regions k_bf[h][kt][...] and v_t[h][kt][...] with
// lane-linear s16x8 stores (perm32 bookkeeping folded into the LDS gather).
__global__ __launch_bounds__(256, 2)
void kv_frag_kernel(const float* __restrict__ pat2,
                    const float* __restrict__ wkv,
                    short* __restrict__ k_bf,
                    short* __restrict__ v_t) {
    __shared__ __align__(16) float spat[32][260];
    __shared__ __align__(16) float kvs[32][129];
    const int kt = blockIdx.x, h = blockIdx.y;
    const int t = threadIdx.x;

    {   // phase 1: pat2 rows -> LDS (coalesced float4 reads)
        const int row = t >> 3;
        const float* src = pat2 + (size_t)(kt * 32 + row) * 256 + (t & 7) * 32;
        float* dst = &spat[row][(t & 7) * 32];
        #pragma unroll
        for (int q = 0; q < 8; q++)
            *(float4*)(dst + q * 4) = *(const float4*)(src + q * 4);
    }
    __syncthreads();

    {   // phase 2: 16 dots per thread -> kvs[pattern][r]
        const int pr = t >> 3;
        const float* srow = &spat[pr][0];
        for (int i = 0; i < 16; i++) {
            const int r = (t & 7) + 8 * i;
            const float* wr = wkv + (size_t)(h * 128 + r) * 256;
            float acc = 0.f;
            for (int i4 = 0; i4 < 64; i4++) {
                const float4 w4 = *(const float4*)(wr + i4 * 4);
                const float4 x4 = *(const float4*)(srow + i4 * 4);
                acc += w4.x * x4.x + w4.y * x4.y + w4.z * x4.z + w4.w * x4.w;
            }
            kvs[pr][r] = acc;
        }
    }
    __syncthreads();

    // phase 3: fragment-order gather + coalesced 16B stores
    const int lane = t & 63;
    const int cl = lane & 15, gq = lane >> 4;
    {   // K region: [f=t>>6][lane*8 + e]; value = kv(pattern pl, d-col r)*0.125
        const int f = t >> 6;
        const int pl = ((f >> 1) << 4) | cl;
        s16x8 o;
        #pragma unroll
        for (int e = 0; e < 8; e++) {
            const int c = (f & 1) * 32 + gq * 8 + e;               // permuted d col
            const int r = (c & ~0x1C) | ((c & 0x18) >> 1) | ((c & 4) << 2); // inv32^-1
            o[e] = (short)f2bf(kvs[pl][r] * 0.125f);
        }
        *(s16x8*)(k_bf + (size_t)h * 32768 + (size_t)kt * 2048 + t * 8) = o;
    }
    {   // V region: [nd=t>>6][lane*8 + e]; value = kv(pattern pl, 64+rd)
        const int nd = t >> 6;
        const int rd = nd * 16 + cl;
        s16x8 o;
        #pragma unroll
        for (int e = 0; e < 8; e++) {
            const int c5 = gq * 8 + e;                             // permuted pattern
            const int pl = (c5 & 3) | ((c5 & 0x18) >> 1) | ((c5 & 4) << 2); // inv32^-1
            o[e] = (short)f2bf(kvs[pl][64 + rd]);
        }
        *(s16x8*)(v_t + (size_t)h * 32768 + (size_t)kt * 2048 + t * 8) = o;
    }
}

// ---------------------------------------------------------------- K2: conv as 3 shifted MFMA GEMMs
__global__ __launch_bounds__(256, 4)
void conv_ln_kernel(const float* __restrict__ x,
                    const short* __restrict__ wck,   // [3][256][256] bf16
                    const float* __restrict__ cb,
                    short* __restrict__ xn_bf) {
    __shared__ __align__(16) short xs[66 * 268];
    const int tid = threadIdx.x;
    const int r0 = blockIdx.x * 64;
    const int pos0 = r0 & 2047;

    #pragma unroll
    for (int it = 0; it < 17; it++) {
        const int idx = tid + it * 256;              // float4 index, 4224 total
        if (idx < 4224) {
            const int row = idx >> 6, c4 = idx & 63;
            float4 v = {0.f, 0.f, 0.f, 0.f};
            if (pos0 - 2 + row >= 0)
                v = *(const float4*)(x + (size_t)(r0 - 2 + row) * 256 + c4 * 4);
            s16x4 o; o[0] = f2bf(v.x); o[1] = f2bf(v.y); o[2] = f2bf(v.z); o[3] = f2bf(v.w);
            *(s16x4*)(xs + row * 268 + c4 * 4) = o;
        }
    }
    __syncthreads();

    const int lane = tid & 63, w = tid >> 6, g = lane >> 4, cl = lane & 15;

    f32x4 acc[4][4];
    #pragma unroll
    for (int mt = 0; mt < 4; mt++)
        #pragma unroll
        for (int nt = 0; nt < 4; nt++) acc[mt][nt] = (f32x4){0.f, 0.f, 0.f, 0.f};

    #pragma unroll
    for (int kk = 0; kk < 3; kk++) {
        const short* wb = wck + kk * 65536;
        for (int s = 0; s < 8; s++) {
            s16x8 a[4];
            #pragma unroll
            for (int mt = 0; mt < 4; mt++)
                a[mt] = *(const s16x8*)(xs + (mt * 16 + cl + kk) * 268 + s * 32 + g * 8);
            #pragma unroll
            for (int nt = 0; nt < 4; nt++) {
                const s16x8 b = *(const s16x8*)(wb + (size_t)(w * 64 + nt * 16 + cl) * 256 + s * 32 + g * 8);
                #pragma unroll
                for (int mt = 0; mt < 4; mt++)
                    acc[mt][nt] = __builtin_amdgcn_mfma_f32_16x16x32_bf16(a[mt], b, acc[mt][nt], 0, 0, 0);
            }
        }
    }

    #pragma unroll
    for (int nt = 0; nt < 4; nt++) {
        const int col = w * 64 + nt * 16 + cl;
        const float b = cb[col];
        #pragma unroll
        for (int mt = 0; mt < 4; mt++)
            #pragma unroll
            for (int r = 0; r < 4; r++) {
                const int row = mt * 16 + g * 4 + r;
                float y = acc[mt][nt][r] + b + x[(size_t)(r0 + row) * 256 + col];
                acc[mt][nt][r] = (y >= 0.f) ? y : 0.01f * y;
            }
    }
    __syncthreads();
    #pragma unroll
    for (int mt = 0; mt < 4; mt++)
        #pragma unroll
        for (int nt = 0; nt < 4; nt++)
            #pragma unroll
            for (int r = 0; r < 4; r++)
                xs[(mt * 16 + g * 4 + r) * 268 + w * 64 + nt * 16 + cl] =
                    (short)f2bf(acc[mt][nt][r]);
    __syncthreads();

    for (int q = 0; q < 16; q++) {
        const int m = w * 16 + q;
        const s16x4 v4 = *(const s16x4*)(xs + m * 268 + lane * 4);
        const float f0 = bf2f((unsigned short)v4[0]), f1 = bf2f((unsigned short)v4[1]);
        const float f2 = bf2f((unsigned short)v4[2]), f3 = bf2f((unsigned short)v4[3]);
        float s = f0 + f1 + f2 + f3;
        #pragma unroll
        for (int off = 32; off; off >>= 1) s += __shfl_xor(s, off);
        const float mu = s * (1.f / 256.f);
        const float d0 = f0 - mu, d1 = f1 - mu, d2 = f2 - mu, d3 = f3 - mu;
        float vv = d0 * d0 + d1 * d1 + d2 * d2 + d3 * d3;
        #pragma unroll
        for (int off = 32; off; off >>= 1) vv += __shfl_xor(vv, off);
        const float rs = rsqrtf(vv * (1.f / 256.f) + EPSF);
        s16x4 o; o[0] = f2bf(d0 * rs); o[1] = f2bf(d1 * rs);
        o[2] = f2bf(d2 * rs); o[3] = f2bf(d3 * rs);
        *(s16x4*)(xn_bf + (size_t)(r0 + m) * 256 + lane * 4) = o;
    }
}

// ---------------------------------------------------------------- K3: fused q-proj + attention
// Grid (T/256, 4), block 256 (4 waves, independent). Wave w owns 64 queries
// [blk*256 + w*64, +64) as 4 groups of 16 (u); block handles heads
// {2*blockIdx.y, +1}. No LDS, no barriers. K/V/wq fragment loads are
// lane-linear contiguous (fragment-order global layout). K frags for kt+1
// prefetched into rotating regs; V frags issued before the exp chain.
__global__ __launch_bounds__(256, 2)
void qattn_kernel(const short* __restrict__ xn_bf,
                  const short* __restrict__ wq_bf,
                  const short* __restrict__ k_bf,
                  const short* __restrict__ v_t,
                  short* __restrict__ ao_bf) {
    const int tid = threadIdx.x;
    const int lane = tid & 63, w = tid >> 6, g = lane >> 4, cl = lane & 15;
    const int q0 = blockIdx.x * 256 + w * 64 + cl;   // group-0 row (+16u for u)
    const int h0 = blockIdx.y * 2;
    const int fo = lane * 8;                         // fragment lane offset (shorts)

    for (int hh = 0; hh < 2; ++hh) {
        const int h = h0 + hh;
        // ---- q-projection, 4 groups (C-layout == scores B-frag, d-permuted)
        f32x4 qacc[4][4];
        #pragma unroll
        for (int u = 0; u < 4; u++)
            #pragma unroll
            for (int nt = 0; nt < 4; nt++) qacc[u][nt] = (f32x4){0.f, 0.f, 0.f, 0.f};
        for (int s = 0; s < 8; ++s) {
            s16x8 aw[4];
            #pragma unroll
            for (int nt = 0; nt < 4; ++nt)
                aw[nt] = *(const s16x8*)(wq_bf + ((size_t)(h * 4 + nt) * 8 + s) * 512 + fo);
            #pragma unroll
            for (int u = 0; u < 4; ++u) {
                const s16x8 bx = *(const s16x8*)(xn_bf + (size_t)(q0 + 16 * u) * 256 + s * 32 + g * 8);
                #pragma unroll
                for (int nt = 0; nt < 4; ++nt)
                    qacc[u][nt] = __builtin_amdgcn_mfma_f32_16x16x32_bf16(aw[nt], bx, qacc[u][nt], 0, 0, 0);
            }
        }
        Bfrag qB[4][2];
        #pragma unroll
        for (int u = 0; u < 4; ++u)
            #pragma unroll
            for (int s = 0; s < 2; ++s) {
                qB[u][s].u[0] = pk_hi(qacc[u][2 * s][0],     qacc[u][2 * s][1]);
                qB[u][s].u[1] = pk_hi(qacc[u][2 * s][2],     qacc[u][2 * s][3]);
                qB[u][s].u[2] = pk_hi(qacc[u][2 * s + 1][0], qacc[u][2 * s + 1][1]);
                qB[u][s].u[3] = pk_hi(qacc[u][2 * s + 1][2], qacc[u][2 * s + 1][3]);
            }

        float lsum[4] = {0.f, 0.f, 0.f, 0.f};
        f32x4 oacc[4][4];
        #pragma unroll
        for (int u = 0; u < 4; u++)
            #pragma unroll
            for (int nd = 0; nd < 4; nd++) oacc[u][nd] = (f32x4){0.f, 0.f, 0.f, 0.f};

        const short* kp = k_bf + (size_t)h * 32768;
        const short* vp = v_t  + (size_t)h * 32768;

        // prologue: K frags for kt=0 (f = 0..3, each lane-linear contiguous)
        s16x8 kn0 = *(const s16x8*)(kp + fo);
        s16x8 kn1 = *(const s16x8*)(kp + fo + 512);
        s16x8 kn2 = *(const s16x8*)(kp + fo + 1024);
        s16x8 kn3 = *(const s16x8*)(kp + fo + 1536);

        for (int kt = 0; kt < 16; ++kt) {
            const s16x8 a00 = kn0, a01 = kn1, a10 = kn2, a11 = kn3;
            if (kt < 15) {                           // prefetch K frags for kt+1
                const short* kn = kp + (kt + 1) * 2048 + fo;
                kn0 = *(const s16x8*)(kn);
                kn1 = *(const s16x8*)(kn + 512);
                kn2 = *(const s16x8*)(kn + 1024);
                kn3 = *(const s16x8*)(kn + 1536);
            }
            // V frags for kt (nd = 0..3), issued before the exp chain
            const short* vb = vp + kt * 2048 + fo;
            const s16x8 va0 = *(const s16x8*)(vb);
            const s16x8 va1 = *(const s16x8*)(vb + 512);
            const s16x8 va2 = *(const s16x8*)(vb + 1024);
            const s16x8 va3 = *(const s16x8*)(vb + 1536);

            // scores S^T: rows kt*32..+32 (2 row-tiles) x 4 query groups
            f32x4 s0[4], s1[4];
            #pragma unroll
            for (int u = 0; u < 4; ++u) {
                s0[u] = (f32x4){0.f, 0.f, 0.f, 0.f};
                s1[u] = (f32x4){0.f, 0.f, 0.f, 0.f};
                s0[u] = __builtin_amdgcn_mfma_f32_16x16x32_bf16(a00, qB[u][0].s, s0[u], 0, 0, 0);
                s0[u] = __builtin_amdgcn_mfma_f32_16x16x32_bf16(a01, qB[u][1].s, s0[u], 0, 0, 0);
                s1[u] = __builtin_amdgcn_mfma_f32_16x16x32_bf16(a10, qB[u][0].s, s1[u], 0, 0, 0);
                s1[u] = __builtin_amdgcn_mfma_f32_16x16x32_bf16(a11, qB[u][1].s, s1[u], 0, 0, 0);
            }

            // softmax numerators (no max: K pre-scaled by 0.125, |s| <~ 1)
            #pragma unroll
            for (int u = 0; u < 4; ++u)
                #pragma unroll
                for (int r = 0; r < 4; ++r) {
                    s0[u][r] = __expf(s0[u][r]); lsum[u] += s0[u][r];
                    s1[u][r] = __expf(s1[u][r]); lsum[u] += s1[u][r];
                }

            Bfrag pB[4];
            #pragma unroll
            for (int u = 0; u < 4; ++u) {
                pB[u].u[0] = pk_hi(s0[u][0], s0[u][1]);
                pB[u].u[1] = pk_hi(s0[u][2], s0[u][3]);
                pB[u].u[2] = pk_hi(s1[u][0], s1[u][1]);
                pB[u].u[3] = pk_hi(s1[u][2], s1[u][3]);
            }

            // PV: O^T += V^T-slice · P^T-slice (patterns kt*32..+32)
            #pragma unroll
            for (int u = 0; u < 4; ++u) {
                oacc[u][0] = __builtin_amdgcn_mfma_f32_16x16x32_bf16(va0, pB[u].s, oacc[u][0], 0, 0, 0);
                oacc[u][1] = __builtin_amdgcn_mfma_f32_16x16x32_bf16(va1, pB[u].s, oacc[u][1], 0, 0, 0);
                oacc[u][2] = __builtin_amdgcn_mfma_f32_16x16x32_bf16(va2, pB[u].s, oacc[u][2], 0, 0, 0);
                oacc[u][3] = __builtin_amdgcn_mfma_f32_16x16x32_bf16(va3, pB[u].s, oacc[u][3], 0, 0, 0);
            }
        }

        // normalize + write O (lane's oacc all belong to its query row)
        #pragma unroll
        for (int u = 0; u < 4; ++u) {
            float s = lsum[u];
            s += __shfl_xor(s, 16);
            s += __shfl_xor(s, 32);
            const float inv = 1.f / s;
            const size_t qr = (size_t)(q0 + u * 16);
            #pragma unroll
            for (int nd = 0; nd < 4; ++nd) {
                const float o0 = oacc[u][nd][0] * inv, o1 = oacc[u][nd][1] * inv;
                const float o2 = oacc[u][nd][2] * inv, o3 = oacc[u][nd][3] * inv;
                const unsigned lo = (unsigned)f2bf(o0) | ((unsigned)f2bf(o1) << 16);
                const unsigned hi = (unsigned)f2bf(o2) | ((unsigned)f2bf(o3) << 16);
                short* dst = ao_bf + qr * 512 + h * 64 + nd * 16 + 4 * g;
                *(unsigned*)(dst)     = lo;
                *(unsigned*)(dst + 2) = hi;
            }
        }
    }
}

// ---------------------------------------------------------------- K4: out-proj MFMA + LN
__global__ __launch_bounds__(256, 4)
void outproj_ln_kernel(const short* __restrict__ ao,
                       const short* __restrict__ wout_bf,
                       const float* __restrict__ bout,
                       float* __restrict__ out) {
    __shared__ __align__(16) char smem[33280];       // A[32][520]s16 == ys[32][260]f32
    short* as = (short*)smem;
    float* ys = (float*)smem;
    const int tid = threadIdx.x;
    const int r0 = blockIdx.x * 32;

    #pragma unroll
    for (int it = 0; it < 8; it++) {
        const int idx = tid + it * 256;              // s16x8 index, 2048 total
        const int row = idx >> 6, c8 = idx & 63;
        const s16x8 v = *(const s16x8*)(ao + (size_t)(r0 + row) * 512 + c8 * 8);
        *(s16x8*)(as + row * 520 + c8 * 8) = v;
    }
    __syncthreads();

    const int lane = tid & 63, w = tid >> 6, g = lane >> 4, cl = lane & 15;

    f32x4 acc[2][4];
    #pragma unroll
    for (int mt = 0; mt < 2; mt++)
        #pragma unroll
        for (int nt = 0; nt < 4; nt++) acc[mt][nt] = (f32x4){0.f, 0.f, 0.f, 0.f};

    for (int s = 0; s < 16; s++) {
        const s16x8 a0 = *(const s16x8*)(as + cl * 520 + s * 32 + g * 8);
        const s16x8 a1 = *(const s16x8*)(as + (16 + cl) * 520 + s * 32 + g * 8);
        #pragma unroll
        for (int nt = 0; nt < 4; nt++) {
            const s16x8 b = *(const s16x8*)(wout_bf + (size_t)(w * 64 + nt * 16 + cl) * 512 + s * 32 + g * 8);
            acc[0][nt] = __builtin_amdgcn_mfma_f32_16x16x32_bf16(a0, b, acc[0][nt], 0, 0, 0);
            acc[1][nt] = __builtin_amdgcn_mfma_f32_16x16x32_bf16(a1, b, acc[1][nt], 0, 0, 0);
        }
    }
    __syncthreads();

    #pragma unroll
    for (int nt = 0; nt < 4; nt++) {
        const int col = w * 64 + nt * 16 + cl;
        const float b = bout[col];
        #pragma unroll
        for (int mt = 0; mt < 2; mt++)
            #pragma unroll
            for (int r = 0; r < 4; r++)
                ys[(mt * 16 + g * 4 + r) * 260 + col] = acc[mt][nt][r] + b;
    }
    __syncthreads();

    for (int q = 0; q < 8; q++) {
        const int m = w * 8 + q;
        const float4 v4 = *(const float4*)(ys + m * 260 + lane * 4);
        float s = v4.x + v4.y + v4.z + v4.w;
        #pragma unroll
        for (int off = 32; off; off >>= 1) s += __shfl_xor(s, off);
        const float mu = s * (1.f / 256.f);
        const float d0 = v4.x - mu, d1 = v4.y - mu, d2 = v4.z - mu, d3 = v4.w - mu;
        float vv = d0 * d0 + d1 * d1 + d2 * d2 + d3 * d3;
        #pragma unroll
        for (int off = 32; off; off >>= 1) vv += __shfl_xor(vv, off);
        const float rs = rsqrtf(vv * (1.f / 256.f) + EPSF);
        float4 o; o.x = d0 * rs; o.y = d1 * rs; o.z = d2 * rs; o.w = d3 * rs;
        *(float4*)(out + (size_t)(r0 + m) * 256 + lane * 4) = o;
    }
}

// ---------------------------------------------------------------- launch
extern "C" void kernel_launch(void* const* d_in, const int* in_sizes, int n_in,
                              void* d_out, int out_size, void* d_ws, size_t ws_size,
                              hipStream_t stream) {
    const float* normed_x = (const float*)d_in[0];
    const float* conv_w   = (const float*)d_in[1];
    const float* conv_b   = (const float*)d_in[2];
    const float* pattern  = (const float*)d_in[3];
    const float* wq       = (const float*)d_in[4];
    const float* wkv      = (const float*)d_in[5];
    const float* wout     = (const float*)d_in[6];
    const float* bout     = (const float*)d_in[7];
    const int T = in_sizes[0] / 256;               // 65536

    char* wsb = (char*)d_ws;
    short* xn_bf  = (short*)(wsb);                             // T*256 bf16 = 32 MB
    short* ao_bf  = (short*)(wsb + (size_t)33554432);          // T*512 bf16 = 64 MB
    short* k_bf   = (short*)(wsb + (size_t)100663296);         // 512 KB
    short* v_t    = (short*)(wsb + (size_t)101187584);         // 512 KB
    short* wq_bf  = (short*)(wsb + (size_t)101711872);         // 256 KB
    short* wout_bf= (short*)(wsb + (size_t)101974016);         // 256 KB
    short* wck    = (short*)(wsb + (size_t)102236160);         // 384 KB
    // pat2 aliases the head of ao_bf: pat2 is dead before qattn writes ao_bf.
    // Keeps workspace high-water mark at the round-4-proven 102,629,376 B.
    float* pat2   = (float*)(wsb + (size_t)33554432);          // 512 KB (alias)
    float* out    = (float*)d_out;

    cvt_kernel<<<512, 256, 0, stream>>>(wq, wout, conv_w, wq_bf, wout_bf, wck);
    pat_ln_kernel<<<512, 256, 0, stream>>>(pattern, pat2);
    kv_frag_kernel<<<dim3(16, 8), 256, 0, stream>>>(pat2, wkv, k_bf, v_t);
    conv_ln_kernel<<<T / 64, 256, 0, stream>>>(normed_x, wck, conv_b, xn_bf);
    qattn_kernel<<<dim3(T / 256, 4), 256, 0, stream>>>(xn_bf, wq_bf, k_bf, v_t, ao_bf);
    outproj_ln_kernel<<<T / 32, 256, 0, stream>>>(ao_bf, wout_bf, bout, out);
}

// Round 7
// 474.231 us; speedup vs baseline: 1.4845x; 1.4845x over previous
//
#include <hip/hip_runtime.h>
#include <hip/hip_bf16.h>
#include <math.h>

// Pipeline:
//  K0 cvt       : wq -> bf16 FRAGMENT-ORDER; wout -> bf16 linear;
//                 conv_w [o][i][k] -> 3x bf16 W_k[o][i]
//  K1a pat_ln   : pat2 = LN(LN(pattern)) fp32                         -> pat2
//                 (pat2 ALIASES the head of ao_bf: live ranges disjoint)
//  K1b kv_frag  : kv = pat2 @ wkv^T, grid (kt=16, h=8, z=2); block owns the
//                 CONTIGUOUS 2KB fragment-order region k_bf[h][kt] (z=0) or
//                 v_t[h][kt] (z=1) -> coalesced 16B stores. Phase-2 dot loop
//                 is ILP-8 (8 interleaved accumulators, single k-walk) —
//                 fixes r6's 263us serial-chain latency stall at 0.5 blk/CU.
//  K2 conv_ln   : y = sum_k Xshift_k @ W_k^T (MFMA) + b + x, leaky, LN -> xn_bf
//  K3 qattn     : FUSED q-proj + S^T-orientation MFMA attention       -> ao_bf
//                 NO LDS, NO barriers. 64 queries/wave (4 groups of 16).
//                 All K/V/wq fragment loads lane-linear (frag-order layout).
//  K4 outproj_ln: ao @ wout^T (MFMA) + bout, LN                       -> d_out
//
// T=65536, D=256, P=512, H=8, dA=64, seqlen=2048.
// perm32(c) permutes bits 2..4: (b4,b3,b2)->(b2,b4,b3); inv32 is its inverse
// (3-cycle: inv32^-1(c) = (c&~0x1C)|((c&0x18)>>1)|((c&4)<<2)).
// Fragment-order for a 16-row x 32-col bf16 MFMA A-frag batch: element
// (row=cl, col=g*8+e) of sub-frag f lives at f*512 + (cl+16*g)*8 + e, so the
// consuming wave (lane = cl+16g) loads s16x8 at base + lane*8: contiguous.
//
// Workspace high-water mark kept at the round-4-proven 102,629,376 bytes.

#define EPSF 1e-5f

typedef short  s16x8 __attribute__((ext_vector_type(8)));
typedef short  s16x4 __attribute__((ext_vector_type(4)));
typedef float  f32x4 __attribute__((ext_vector_type(4)));

__device__ __forceinline__ unsigned short f2bf(float f) {
    union { float f; unsigned u; } v; v.f = f;
    unsigned r = (v.u + 0x7fffu + ((v.u >> 16) & 1u)) >> 16;   // RNE
    return (unsigned short)r;
}
__device__ __forceinline__ float bf2f(unsigned short h) {
    union { unsigned u; float f; } v; v.u = ((unsigned)h) << 16;
    return v.f;
}
__device__ __forceinline__ unsigned fbits(float f) {
    union { float f; unsigned u; } v; v.f = f; return v.u;
}
// pack two floats' high halves (truncate-to-bf16): low16 = lo, high16 = hi
__device__ __forceinline__ unsigned pk_hi(float lo, float hi) {
    return __builtin_amdgcn_perm(fbits(hi), fbits(lo), 0x07060302u);
}
__device__ __forceinline__ int inv32(int t) {   // inverse of perm32, touches bits 2..4
    return (t & ~31) | ((t & 0x0C) << 1) | ((t & 0x10) >> 2) | (t & 3);
}

union Bfrag { unsigned u[4]; s16x8 s; };

// ---------------------------------------------------------------- K0
__global__ void cvt_kernel(const float* __restrict__ wq,
                           const float* __restrict__ wout,
                           const float* __restrict__ cw,
                           short* __restrict__ wq_bf,     // fragment-order
                           short* __restrict__ wout_bf,   // linear
                           short* __restrict__ wck) {
    const int b = blockIdx.x, tid = threadIdx.x;
    if (b < 128) {
        // wq [512][256] -> fragment order
        const int i = (b * 256 + tid) * 4;
        const int R = i >> 8, C = i & 255;
        const float4 x = *(const float4*)(wq + i);
        s16x4 o; o[0] = f2bf(x.x); o[1] = f2bf(x.y); o[2] = f2bf(x.z); o[3] = f2bf(x.w);
        const int off = ((R >> 6) * 32 + ((R >> 4) & 3) * 8 + (C >> 5)) * 512
                      + ((R & 15) + ((C >> 3) & 3) * 16) * 8 + (C & 7);
        *(s16x4*)(wq_bf + off) = o;
    } else if (b < 256) {
        const int i = ((b - 128) * 256 + tid) * 4;
        const float4 x = *(const float4*)(wout + i);
        s16x4 o; o[0] = f2bf(x.x); o[1] = f2bf(x.y); o[2] = f2bf(x.z); o[3] = f2bf(x.w);
        *(s16x4*)(wout_bf + i) = o;
    } else {
        const int idx = (b - 256) * 256 + tid;          // (o,i) pair, 65536 total
        const float* p = cw + (size_t)idx * 3;
        wck[idx]              = (short)f2bf(p[0]);
        wck[65536 + idx]      = (short)f2bf(p[1]);
        wck[131072 + idx]     = (short)f2bf(p[2]);
    }
}

// ---------------------------------------------------------------- K1a: LN(LN(pattern)) -> pat2 fp32
__global__ void pat_ln_kernel(const float* __restrict__ pattern,
                              float* __restrict__ pat2) {
    __shared__ float scr[4];
    const int w = blockIdx.x;
    const int tid = threadIdx.x;
    const int lane = tid & 63, wav = tid >> 6;

    float v = pattern[(size_t)w * 256 + tid];

    float s = v;
    #pragma unroll
    for (int off = 32; off; off >>= 1) s += __shfl_xor(s, off);
    if (lane == 0) scr[wav] = s;
    __syncthreads();
    float mu = (scr[0] + scr[1] + scr[2] + scr[3]) * (1.f / 256.f);
    __syncthreads();
    float d = v - mu;
    float s2 = d * d;
    #pragma unroll
    for (int off = 32; off; off >>= 1) s2 += __shfl_xor(s2, off);
    if (lane == 0) scr[wav] = s2;
    __syncthreads();
    float var = (scr[0] + scr[1] + scr[2] + scr[3]) * (1.f / 256.f);
    float x1 = d * rsqrtf(var + EPSF);
    __syncthreads();

    s = x1;
    #pragma unroll
    for (int off = 32; off; off >>= 1) s += __shfl_xor(s, off);
    if (lane == 0) scr[wav] = s;
    __syncthreads();
    mu = (scr[0] + scr[1] + scr[2] + scr[3]) * (1.f / 256.f);
    __syncthreads();
    d = x1 - mu;
    s2 = d * d;
    #pragma unroll
    for (int off = 32; off; off >>= 1) s2 += __shfl_xor(s2, off);
    if (lane == 0) scr[wav] = s2;
    __syncthreads();
    var = (scr[0] + scr[1] + scr[2] + scr[3]) * (1.f / 256.f);
    pat2[(size_t)w * 256 + tid] = d * rsqrtf(var + EPSF);
}

// ---------------------------------------------------------------- K1b: kv GEMM -> fragment-order, coalesced
// Grid (kt=16, h=8, z=2), 256 threads. Block computes patterns [kt*32,+32) x
// wkv rows [h*128 + z*64, +64), stages 32x64 fp32 in LDS, then writes the
// contiguous 2KB-short region k_bf[h][kt] (z=0, scaled 0.125) or v_t[h][kt]
// (z=1) with lane-linear s16x8 stores. Phase 2: single k-walk feeding 8
// interleaved accumulators per thread (ILP-8, no serial-dot stall).
__global__ __launch_bounds__(256, 2)
void kv_frag_kernel(const float* __restrict__ pat2,
                    const float* __restrict__ wkv,
                    short* __restrict__ k_bf,
                    short* __restrict__ v_t) {
    __shared__ __align__(16) float spat[32][260];
    __shared__ __align__(16) float kvs[32][65];
    const int kt = blockIdx.x, h = blockIdx.y, z = blockIdx.z;
    const int t = threadIdx.x;

    {   // phase 1: pat2 rows -> LDS (coalesced float4 reads)
        const int row = t >> 3;
        const float* src = pat2 + (size_t)(kt * 32 + row) * 256 + (t & 7) * 32;
        float* dst = &spat[row][(t & 7) * 32];
        #pragma unroll
        for (int q = 0; q < 8; q++)
            *(float4*)(dst + q * 4) = *(const float4*)(src + q * 4);
    }
    __syncthreads();

    {   // phase 2: 8 interleaved dots per thread -> kvs[pattern][r]
        const int pr = t >> 3, rb = t & 7;
        const float* srow = &spat[pr][0];
        const float* wbase = wkv + (size_t)(h * 128 + z * 64 + rb) * 256;
        float acc[8] = {0.f, 0.f, 0.f, 0.f, 0.f, 0.f, 0.f, 0.f};
        for (int i4 = 0; i4 < 64; i4++) {
            const float4 x4 = *(const float4*)(srow + i4 * 4);
            #pragma unroll
            for (int i = 0; i < 8; i++) {
                const float4 w4 = *(const float4*)(wbase + (size_t)i * 8 * 256 + i4 * 4);
                acc[i] += w4.x * x4.x + w4.y * x4.y + w4.z * x4.z + w4.w * x4.w;
            }
        }
        #pragma unroll
        for (int i = 0; i < 8; i++)
            kvs[pr][rb + 8 * i] = acc[i];
    }
    __syncthreads();

    // phase 3: fragment-order gather + coalesced 16B stores
    const int lane = t & 63;
    const int cl = lane & 15, gq = lane >> 4;
    if (z == 0) {
        // K region: [f=t>>6][lane*8 + e]; value = kv(pattern pl, d-col r)*0.125
        const int f = t >> 6;
        const int pl = ((f >> 1) << 4) | cl;
        s16x8 o;
        #pragma unroll
        for (int e = 0; e < 8; e++) {
            const int c = (f & 1) * 32 + gq * 8 + e;               // permuted d col
            const int r = (c & ~0x1C) | ((c & 0x18) >> 1) | ((c & 4) << 2); // inv32^-1
            o[e] = (short)f2bf(kvs[pl][r] * 0.125f);
        }
        *(s16x8*)(k_bf + (size_t)h * 32768 + (size_t)kt * 2048 + t * 8) = o;
    } else {
        // V region: [nd=t>>6][lane*8 + e]; value = kv(pattern pl, 64+rd)
        const int nd = t >> 6;
        const int rd = nd * 16 + cl;
        s16x8 o;
        #pragma unroll
        for (int e = 0; e < 8; e++) {
            const int c5 = gq * 8 + e;                             // permuted pattern
            const int pl = (c5 & 3) | ((c5 & 0x18) >> 1) | ((c5 & 4) << 2); // inv32^-1
            o[e] = (short)f2bf(kvs[pl][rd]);
        }
        *(s16x8*)(v_t + (size_t)h * 32768 + (size_t)kt * 2048 + t * 8) = o;
    }
}

// ---------------------------------------------------------------- K2: conv as 3 shifted MFMA GEMMs
__global__ __launch_bounds__(256, 4)
void conv_ln_kernel(const float* __restrict__ x,
                    const short* __restrict__ wck,   // [3][256][256] bf16
                    const float* __restrict__ cb,
                    short* __restrict__ xn_bf) {
    __shared__ __align__(16) short xs[66 * 268];
    const int tid = threadIdx.x;
    const int r0 = blockIdx.x * 64;
    const int pos0 = r0 & 2047;

    #pragma unroll
    for (int it = 0; it < 17; it++) {
        const int idx = tid + it * 256;              // float4 index, 4224 total
        if (idx < 4224) {
            const int row = idx >> 6, c4 = idx & 63;
            float4 v = {0.f, 0.f, 0.f, 0.f};
            if (pos0 - 2 + row >= 0)
                v = *(const float4*)(x + (size_t)(r0 - 2 + row) * 256 + c4 * 4);
            s16x4 o; o[0] = f2bf(v.x); o[1] = f2bf(v.y); o[2] = f2bf(v.z); o[3] = f2bf(v.w);
            *(s16x4*)(xs + row * 268 + c4 * 4) = o;
        }
    }
    __syncthreads();

    const int lane = tid & 63, w = tid >> 6, g = lane >> 4, cl = lane & 15;

    f32x4 acc[4][4];
    #pragma unroll
    for (int mt = 0; mt < 4; mt++)
        #pragma unroll
        for (int nt = 0; nt < 4; nt++) acc[mt][nt] = (f32x4){0.f, 0.f, 0.f, 0.f};

    #pragma unroll
    for (int kk = 0; kk < 3; kk++) {
        const short* wb = wck + kk * 65536;
        for (int s = 0; s < 8; s++) {
            s16x8 a[4];
            #pragma unroll
            for (int mt = 0; mt < 4; mt++)
                a[mt] = *(const s16x8*)(xs + (mt * 16 + cl + kk) * 268 + s * 32 + g * 8);
            #pragma unroll
            for (int nt = 0; nt < 4; nt++) {
                const s16x8 b = *(const s16x8*)(wb + (size_t)(w * 64 + nt * 16 + cl) * 256 + s * 32 + g * 8);
                #pragma unroll
                for (int mt = 0; mt < 4; mt++)
                    acc[mt][nt] = __builtin_amdgcn_mfma_f32_16x16x32_bf16(a[mt], b, acc[mt][nt], 0, 0, 0);
            }
        }
    }

    #pragma unroll
    for (int nt = 0; nt < 4; nt++) {
        const int col = w * 64 + nt * 16 + cl;
        const float b = cb[col];
        #pragma unroll
        for (int mt = 0; mt < 4; mt++)
            #pragma unroll
            for (int r = 0; r < 4; r++) {
                const int row = mt * 16 + g * 4 + r;
                float y = acc[mt][nt][r] + b + x[(size_t)(r0 + row) * 256 + col];
                acc[mt][nt][r] = (y >= 0.f) ? y : 0.01f * y;
            }
    }
    __syncthreads();
    #pragma unroll
    for (int mt = 0; mt < 4; mt++)
        #pragma unroll
        for (int nt = 0; nt < 4; nt++)
            #pragma unroll
            for (int r = 0; r < 4; r++)
                xs[(mt * 16 + g * 4 + r) * 268 + w * 64 + nt * 16 + cl] =
                    (short)f2bf(acc[mt][nt][r]);
    __syncthreads();

    for (int q = 0; q < 16; q++) {
        const int m = w * 16 + q;
        const s16x4 v4 = *(const s16x4*)(xs + m * 268 + lane * 4);
        const float f0 = bf2f((unsigned short)v4[0]), f1 = bf2f((unsigned short)v4[1]);
        const float f2 = bf2f((unsigned short)v4[2]), f3 = bf2f((unsigned short)v4[3]);
        float s = f0 + f1 + f2 + f3;
        #pragma unroll
        for (int off = 32; off; off >>= 1) s += __shfl_xor(s, off);
        const float mu = s * (1.f / 256.f);
        const float d0 = f0 - mu, d1 = f1 - mu, d2 = f2 - mu, d3 = f3 - mu;
        float vv = d0 * d0 + d1 * d1 + d2 * d2 + d3 * d3;
        #pragma unroll
        for (int off = 32; off; off >>= 1) vv += __shfl_xor(vv, off);
        const float rs = rsqrtf(vv * (1.f / 256.f) + EPSF);
        s16x4 o; o[0] = f2bf(d0 * rs); o[1] = f2bf(d1 * rs);
        o[2] = f2bf(d2 * rs); o[3] = f2bf(d3 * rs);
        *(s16x4*)(xn_bf + (size_t)(r0 + m) * 256 + lane * 4) = o;
    }
}

// ---------------------------------------------------------------- K3: fused q-proj + attention
// Grid (T/256, 4), block 256 (4 waves, independent). Wave w owns 64 queries
// [blk*256 + w*64, +64) as 4 groups of 16 (u); block handles heads
// {2*blockIdx.y, +1}. No LDS, no barriers. K/V/wq fragment loads are
// lane-linear contiguous (fragment-order global layout). K frags for kt+1
// prefetched into rotating regs; V frags issued before the exp chain.
__global__ __launch_bounds__(256, 2)
void qattn_kernel(const short* __restrict__ xn_bf,
                  const short* __restrict__ wq_bf,
                  const short* __restrict__ k_bf,
                  const short* __restrict__ v_t,
                  short* __restrict__ ao_bf) {
    const int tid = threadIdx.x;
    const int lane = tid & 63, w = tid >> 6, g = lane >> 4, cl = lane & 15;
    const int q0 = blockIdx.x * 256 + w * 64 + cl;   // group-0 row (+16u for u)
    const int h0 = blockIdx.y * 2;
    const int fo = lane * 8;                         // fragment lane offset (shorts)

    for (int hh = 0; hh < 2; ++hh) {
        const int h = h0 + hh;
        // ---- q-projection, 4 groups (C-layout == scores B-frag, d-permuted)
        f32x4 qacc[4][4];
        #pragma unroll
        for (int u = 0; u < 4; u++)
            #pragma unroll
            for (int nt = 0; nt < 4; nt++) qacc[u][nt] = (f32x4){0.f, 0.f, 0.f, 0.f};
        for (int s = 0; s < 8; ++s) {
            s16x8 aw[4];
            #pragma unroll
            for (int nt = 0; nt < 4; ++nt)
                aw[nt] = *(const s16x8*)(wq_bf + ((size_t)(h * 4 + nt) * 8 + s) * 512 + fo);
            #pragma unroll
            for (int u = 0; u < 4; ++u) {
                const s16x8 bx = *(const s16x8*)(xn_bf + (size_t)(q0 + 16 * u) * 256 + s * 32 + g * 8);
                #pragma unroll
                for (int nt = 0; nt < 4; ++nt)
                    qacc[u][nt] = __builtin_amdgcn_mfma_f32_16x16x32_bf16(aw[nt], bx, qacc[u][nt], 0, 0, 0);
            }
        }
        Bfrag qB[4][2];
        #pragma unroll
        for (int u = 0; u < 4; ++u)
            #pragma unroll
            for (int s = 0; s < 2; ++s) {
                qB[u][s].u[0] = pk_hi(qacc[u][2 * s][0],     qacc[u][2 * s][1]);
                qB[u][s].u[1] = pk_hi(qacc[u][2 * s][2],     qacc[u][2 * s][3]);
                qB[u][s].u[2] = pk_hi(qacc[u][2 * s + 1][0], qacc[u][2 * s + 1][1]);
                qB[u][s].u[3] = pk_hi(qacc[u][2 * s + 1][2], qacc[u][2 * s + 1][3]);
            }

        float lsum[4] = {0.f, 0.f, 0.f, 0.f};
        f32x4 oacc[4][4];
        #pragma unroll
        for (int u = 0; u < 4; u++)
            #pragma unroll
            for (int nd = 0; nd < 4; nd++) oacc[u][nd] = (f32x4){0.f, 0.f, 0.f, 0.f};

        const short* kp = k_bf + (size_t)h * 32768;
        const short* vp = v_t  + (size_t)h * 32768;

        // prologue: K frags for kt=0 (f = 0..3, each lane-linear contiguous)
        s16x8 kn0 = *(const s16x8*)(kp + fo);
        s16x8 kn1 = *(const s16x8*)(kp + fo + 512);
        s16x8 kn2 = *(const s16x8*)(kp + fo + 1024);
        s16x8 kn3 = *(const s16x8*)(kp + fo + 1536);

        for (int kt = 0; kt < 16; ++kt) {
            const s16x8 a00 = kn0, a01 = kn1, a10 = kn2, a11 = kn3;
            if (kt < 15) {                           // prefetch K frags for kt+1
                const short* kn = kp + (kt + 1) * 2048 + fo;
                kn0 = *(const s16x8*)(kn);
                kn1 = *(const s16x8*)(kn + 512);
                kn2 = *(const s16x8*)(kn + 1024);
                kn3 = *(const s16x8*)(kn + 1536);
            }
            // V frags for kt (nd = 0..3), issued before the exp chain
            const short* vb = vp + kt * 2048 + fo;
            const s16x8 va0 = *(const s16x8*)(vb);
            const s16x8 va1 = *(const s16x8*)(vb + 512);
            const s16x8 va2 = *(const s16x8*)(vb + 1024);
            const s16x8 va3 = *(const s16x8*)(vb + 1536);

            // scores S^T: rows kt*32..+32 (2 row-tiles) x 4 query groups
            f32x4 s0[4], s1[4];
            #pragma unroll
            for (int u = 0; u < 4; ++u) {
                s0[u] = (f32x4){0.f, 0.f, 0.f, 0.f};
                s1[u] = (f32x4){0.f, 0.f, 0.f, 0.f};
                s0[u] = __builtin_amdgcn_mfma_f32_16x16x32_bf16(a00, qB[u][0].s, s0[u], 0, 0, 0);
                s0[u] = __builtin_amdgcn_mfma_f32_16x16x32_bf16(a01, qB[u][1].s, s0[u], 0, 0, 0);
                s1[u] = __builtin_amdgcn_mfma_f32_16x16x32_bf16(a10, qB[u][0].s, s1[u], 0, 0, 0);
                s1[u] = __builtin_amdgcn_mfma_f32_16x16x32_bf16(a11, qB[u][1].s, s1[u], 0, 0, 0);
            }

            // softmax numerators (no max: K pre-scaled by 0.125, |s| <~ 1)
            #pragma unroll
            for (int u = 0; u < 4; ++u)
                #pragma unroll
                for (int r = 0; r < 4; ++r) {
                    s0[u][r] = __expf(s0[u][r]); lsum[u] += s0[u][r];
                    s1[u][r] = __expf(s1[u][r]); lsum[u] += s1[u][r];
                }

            Bfrag pB[4];
            #pragma unroll
            for (int u = 0; u < 4; ++u) {
                pB[u].u[0] = pk_hi(s0[u][0], s0[u][1]);
                pB[u].u[1] = pk_hi(s0[u][2], s0[u][3]);
                pB[u].u[2] = pk_hi(s1[u][0], s1[u][1]);
                pB[u].u[3] = pk_hi(s1[u][2], s1[u][3]);
            }

            // PV: O^T += V^T-slice · P^T-slice (patterns kt*32..+32)
            #pragma unroll
            for (int u = 0; u < 4; ++u) {
                oacc[u][0] = __builtin_amdgcn_mfma_f32_16x16x32_bf16(va0, pB[u].s, oacc[u][0], 0, 0, 0);
                oacc[u][1] = __builtin_amdgcn_mfma_f32_16x16x32_bf16(va1, pB[u].s, oacc[u][1], 0, 0, 0);
                oacc[u][2] = __builtin_amdgcn_mfma_f32_16x16x32_bf16(va2, pB[u].s, oacc[u][2], 0, 0, 0);
                oacc[u][3] = __builtin_amdgcn_mfma_f32_16x16x32_bf16(va3, pB[u].s, oacc[u][3], 0, 0, 0);
            }
        }

        // normalize + write O (lane's oacc all belong to its query row)
        #pragma unroll
        for (int u = 0; u < 4; ++u) {
            float s = lsum[u];
            s += __shfl_xor(s, 16);
            s += __shfl_xor(s, 32);
            const float inv = 1.f / s;
            const size_t qr = (size_t)(q0 + u * 16);
            #pragma unroll
            for (int nd = 0; nd < 4; ++nd) {
                const float o0 = oacc[u][nd][0] * inv, o1 = oacc[u][nd][1] * inv;
                const float o2 = oacc[u][nd][2] * inv, o3 = oacc[u][nd][3] * inv;
                const unsigned lo = (unsigned)f2bf(o0) | ((unsigned)f2bf(o1) << 16);
                const unsigned hi = (unsigned)f2bf(o2) | ((unsigned)f2bf(o3) << 16);
                short* dst = ao_bf + qr * 512 + h * 64 + nd * 16 + 4 * g;
                *(unsigned*)(dst)     = lo;
                *(unsigned*)(dst + 2) = hi;
            }
        }
    }
}

// ---------------------------------------------------------------- K4: out-proj MFMA + LN
__global__ __launch_bounds__(256, 4)
void outproj_ln_kernel(const short* __restrict__ ao,
                       const short* __restrict__ wout_bf,
                       const float* __restrict__ bout,
                       float* __restrict__ out) {
    __shared__ __align__(16) char smem[33280];       // A[32][520]s16 == ys[32][260]f32
    short* as = (short*)smem;
    float* ys = (float*)smem;
    const int tid = threadIdx.x;
    const int r0 = blockIdx.x * 32;

    #pragma unroll
    for (int it = 0; it < 8; it++) {
        const int idx = tid + it * 256;              // s16x8 index, 2048 total
        const int row = idx >> 6, c8 = idx & 63;
        const s16x8 v = *(const s16x8*)(ao + (size_t)(r0 + row) * 512 + c8 * 8);
        *(s16x8*)(as + row * 520 + c8 * 8) = v;
    }
    __syncthreads();

    const int lane = tid & 63, w = tid >> 6, g = lane >> 4, cl = lane & 15;

    f32x4 acc[2][4];
    #pragma unroll
    for (int mt = 0; mt < 2; mt++)
        #pragma unroll
        for (int nt = 0; nt < 4; nt++) acc[mt][nt] = (f32x4){0.f, 0.f, 0.f, 0.f};

    for (int s = 0; s < 16; s++) {
        const s16x8 a0 = *(const s16x8*)(as + cl * 520 + s * 32 + g * 8);
        const s16x8 a1 = *(const s16x8*)(as + (16 + cl) * 520 + s * 32 + g * 8);
        #pragma unroll
        for (int nt = 0; nt < 4; nt++) {
            const s16x8 b = *(const s16x8*)(wout_bf + (size_t)(w * 64 + nt * 16 + cl) * 512 + s * 32 + g * 8);
            acc[0][nt] = __builtin_amdgcn_mfma_f32_16x16x32_bf16(a0, b, acc[0][nt], 0, 0, 0);
            acc[1][nt] = __builtin_amdgcn_mfma_f32_16x16x32_bf16(a1, b, acc[1][nt], 0, 0, 0);
        }
    }
    __syncthreads();

    #pragma unroll
    for (int nt = 0; nt < 4; nt++) {
        const int col = w * 64 + nt * 16 + cl;
        const float b = bout[col];
        #pragma unroll
        for (int mt = 0; mt < 2; mt++)
            #pragma unroll
            for (int r = 0; r < 4; r++)
                ys[(mt * 16 + g * 4 + r) * 260 + col] = acc[mt][nt][r] + b;
    }
    __syncthreads();

    for (int q = 0; q < 8; q++) {
        const int m = w * 8 + q;
        const float4 v4 = *(const float4*)(ys + m * 260 + lane * 4);
        float s = v4.x + v4.y + v4.z + v4.w;
        #pragma unroll
        for (int off = 32; off; off >>= 1) s += __shfl_xor(s, off);
        const float mu = s * (1.f / 256.f);
        const float d0 = v4.x - mu, d1 = v4.y - mu, d2 = v4.z - mu, d3 = v4.w - mu;
        float vv = d0 * d0 + d1 * d1 + d2 * d2 + d3 * d3;
        #pragma unroll
        for (int off = 32; off; off >>= 1) vv += __shfl_xor(vv, off);
        const float rs = rsqrtf(vv * (1.f / 256.f) + EPSF);
        float4 o; o.x = d0 * rs; o.y = d1 * rs; o.z = d2 * rs; o.w = d3 * rs;
        *(float4*)(out + (size_t)(r0 + m) * 256 + lane * 4) = o;
    }
}

// ---------------------------------------------------------------- launch
extern "C" void kernel_launch(void* const* d_in, const int* in_sizes, int n_in,
                              void* d_out, int out_size, void* d_ws, size_t ws_size,
                              hipStream_t stream) {
    const float* normed_x = (const float*)d_in[0];
    const float* conv_w   = (const float*)d_in[1];
    const float* conv_b   = (const float*)d_in[2];
    const float* pattern  = (const float*)d_in[3];
    const float* wq       = (const float*)d_in[4];
    const float* wkv      = (const float*)d_in[5];
    const float* wout     = (const float*)d_in[6];
    const float* bout     = (const float*)d_in[7];
    const int T = in_sizes[0] / 256;               // 65536

    char* wsb = (char*)d_ws;
    short* xn_bf  = (short*)(wsb);                             // T*256 bf16 = 32 MB
    short* ao_bf  = (short*)(wsb + (size_t)33554432);          // T*512 bf16 = 64 MB
    short* k_bf   = (short*)(wsb + (size_t)100663296);         // 512 KB
    short* v_t    = (short*)(wsb + (size_t)101187584);         // 512 KB
    short* wq_bf  = (short*)(wsb + (size_t)101711872);         // 256 KB
    short* wout_bf= (short*)(wsb + (size_t)101974016);         // 256 KB
    short* wck    = (short*)(wsb + (size_t)102236160);         // 384 KB
    // pat2 aliases the head of ao_bf: pat2 is dead before qattn writes ao_bf.
    float* pat2   = (float*)(wsb + (size_t)33554432);          // 512 KB (alias)
    float* out    = (float*)d_out;

    cvt_kernel<<<512, 256, 0, stream>>>(wq, wout, conv_w, wq_bf, wout_bf, wck);
    pat_ln_kernel<<<512, 256, 0, stream>>>(pattern, pat2);
    kv_frag_kernel<<<dim3(16, 8, 2), 256, 0, stream>>>(pat2, wkv, k_bf, v_t);
    conv_ln_kernel<<<T / 64, 256, 0, stream>>>(normed_x, wck, conv_b, xn_bf);
    qattn_kernel<<<dim3(T / 256, 4), 256, 0, stream>>>(xn_bf, wq_bf, k_bf, v_t, ao_bf);
    outproj_ln_kernel<<<T / 32, 256, 0, stream>>>(ao_bf, wout_bf, bout, out);
}

// Round 8
// 462.076 us; speedup vs baseline: 1.5235x; 1.0263x over previous
//
#include <hip/hip_runtime.h>
#include <hip/hip_bf16.h>
#include <math.h>

// Pipeline:
//  K0 cvt       : wq, wout, conv_w -> bf16 FRAGMENT-ORDER (all three weight
//                 buffers are consumed as lane-linear MFMA fragments)
//  K1a pat_ln   : pat2 = LN(LN(pattern)) fp32  (aliases head of ao buffer)
//  K1b kv_frag  : kv = pat2 @ wkv^T -> k_bf / v_t fragment-order, coalesced.
//                 K prescale = 0.125*log2(e) (exp2 softmax downstream).
//  K2 conv_ln   : y = sum_k Xshift_k @ W_k^T (MFMA) + b + x, leaky, LN -> xn_bf
//                 B-frags lane-linear from wck frag-order.
//  K3 qattn     : FUSED q-proj + S^T-orientation MFMA attention -> ao (frag-order)
//                 NO LDS/barriers; exp2 softmax; O stored in MFMA-A-fragment
//                 order: each (u,nd) store covers a DENSE 512B range (fixes
//                 r7's 2.5x ao write amplification + RMW fetch).
//  K4 outproj_ln: A-frags lane-linear DIRECT from ao frag-order (no staging),
//                 B-frags lane-linear from wout frag-order; + bout, LN -> out
//
// T=65536, D=256, P=512, H=8, dA=64, seqlen=2048.
// perm32(c) permutes bits 2..4: (b4,b3,b2)->(b2,b4,b3); inv32^-1(c) =
// (c&~0x1C)|((c&0x18)>>1)|((c&4)<<2).
// Fragment-order (16x16x32 A/B frag): element (row=l&15, col=(l>>4)*8+e)
// lives at l*8+e -> consuming wave loads s16x8 at base + lane*8 (contiguous).
// ao frag-order: [rt=q>>4][s=c>>5][ (q&15 + 16*((c>>3)&3))*8 + (c&7) ].
// Workspace high-water mark: 102,629,376 bytes (round-4-proven).

#define EPSF 1e-5f
#define KSCALE 0.18033688f   // 0.125 * log2(e)

typedef short  s16x8 __attribute__((ext_vector_type(8)));
typedef short  s16x4 __attribute__((ext_vector_type(4)));
typedef float  f32x4 __attribute__((ext_vector_type(4)));

__device__ __forceinline__ unsigned short f2bf(float f) {
    union { float f; unsigned u; } v; v.f = f;
    unsigned r = (v.u + 0x7fffu + ((v.u >> 16) & 1u)) >> 16;   // RNE
    return (unsigned short)r;
}
__device__ __forceinline__ float bf2f(unsigned short h) {
    union { unsigned u; float f; } v; v.u = ((unsigned)h) << 16;
    return v.f;
}
__device__ __forceinline__ unsigned fbits(float f) {
    union { float f; unsigned u; } v; v.f = f; return v.u;
}
// pack two floats' high halves (truncate-to-bf16): low16 = lo, high16 = hi
__device__ __forceinline__ unsigned pk_hi(float lo, float hi) {
    return __builtin_amdgcn_perm(fbits(hi), fbits(lo), 0x07060302u);
}

union Bfrag { unsigned u[4]; s16x8 s; };

// ---------------------------------------------------------------- K0
__global__ void cvt_kernel(const float* __restrict__ wq,
                           const float* __restrict__ wout,
                           const float* __restrict__ cw,
                           short* __restrict__ wq_bf,     // fragment-order
                           short* __restrict__ wout_bf,   // fragment-order
                           short* __restrict__ wck) {     // fragment-order
    const int b = blockIdx.x, tid = threadIdx.x;
    if (b < 128) {
        // wq [512][256] -> fragment order [R>>6 grouping kept from r4]
        const int i = (b * 256 + tid) * 4;
        const int R = i >> 8, C = i & 255;
        const float4 x = *(const float4*)(wq + i);
        s16x4 o; o[0] = f2bf(x.x); o[1] = f2bf(x.y); o[2] = f2bf(x.z); o[3] = f2bf(x.w);
        const int off = ((R >> 6) * 32 + ((R >> 4) & 3) * 8 + (C >> 5)) * 512
                      + ((R & 15) + ((C >> 3) & 3) * 16) * 8 + (C & 7);
        *(s16x4*)(wq_bf + off) = o;
    } else if (b < 256) {
        // wout [256][512] -> fragment order [ct=R>>4][s=C>>5]
        const int i = ((b - 128) * 256 + tid) * 4;
        const int R = i >> 9, C = i & 511;
        const float4 x = *(const float4*)(wout + i);
        s16x4 o; o[0] = f2bf(x.x); o[1] = f2bf(x.y); o[2] = f2bf(x.z); o[3] = f2bf(x.w);
        const int off = ((R >> 4) * 16 + (C >> 5)) * 512
                      + ((R & 15) + ((C >> 3) & 3) * 16) * 8 + (C & 7);
        *(s16x4*)(wout_bf + off) = o;
    } else {
        // conv_w [o][i][k] -> 3x fragment-order W_k  [ct=o>>4][s=i>>5]
        const int idx = (b - 256) * 256 + tid;          // (o,i) pair, 65536 total
        const int o = idx >> 8, i = idx & 255;
        const float* p = cw + (size_t)idx * 3;
        const int off = ((o >> 4) * 8 + (i >> 5)) * 512
                      + ((o & 15) + ((i >> 3) & 3) * 16) * 8 + (i & 7);
        wck[off]           = (short)f2bf(p[0]);
        wck[65536 + off]   = (short)f2bf(p[1]);
        wck[131072 + off]  = (short)f2bf(p[2]);
    }
}

// ---------------------------------------------------------------- K1a: LN(LN(pattern)) -> pat2 fp32
__global__ void pat_ln_kernel(const float* __restrict__ pattern,
                              float* __restrict__ pat2) {
    __shared__ float scr[4];
    const int w = blockIdx.x;
    const int tid = threadIdx.x;
    const int lane = tid & 63, wav = tid >> 6;

    float v = pattern[(size_t)w * 256 + tid];

    float s = v;
    #pragma unroll
    for (int off = 32; off; off >>= 1) s += __shfl_xor(s, off);
    if (lane == 0) scr[wav] = s;
    __syncthreads();
    float mu = (scr[0] + scr[1] + scr[2] + scr[3]) * (1.f / 256.f);
    __syncthreads();
    float d = v - mu;
    float s2 = d * d;
    #pragma unroll
    for (int off = 32; off; off >>= 1) s2 += __shfl_xor(s2, off);
    if (lane == 0) scr[wav] = s2;
    __syncthreads();
    float var = (scr[0] + scr[1] + scr[2] + scr[3]) * (1.f / 256.f);
    float x1 = d * rsqrtf(var + EPSF);
    __syncthreads();

    s = x1;
    #pragma unroll
    for (int off = 32; off; off >>= 1) s += __shfl_xor(s, off);
    if (lane == 0) scr[wav] = s;
    __syncthreads();
    mu = (scr[0] + scr[1] + scr[2] + scr[3]) * (1.f / 256.f);
    __syncthreads();
    d = x1 - mu;
    s2 = d * d;
    #pragma unroll
    for (int off = 32; off; off >>= 1) s2 += __shfl_xor(s2, off);
    if (lane == 0) scr[wav] = s2;
    __syncthreads();
    var = (scr[0] + scr[1] + scr[2] + scr[3]) * (1.f / 256.f);
    pat2[(size_t)w * 256 + tid] = d * rsqrtf(var + EPSF);
}

// ---------------------------------------------------------------- K1b: kv GEMM -> fragment-order, coalesced
// Grid (kt=16, h=8, z=2), 256 threads. ILP-8 dot loop; coalesced 16B stores.
__global__ __launch_bounds__(256, 2)
void kv_frag_kernel(const float* __restrict__ pat2,
                    const float* __restrict__ wkv,
                    short* __restrict__ k_bf,
                    short* __restrict__ v_t) {
    __shared__ __align__(16) float spat[32][260];
    __shared__ __align__(16) float kvs[32][65];
    const int kt = blockIdx.x, h = blockIdx.y, z = blockIdx.z;
    const int t = threadIdx.x;

    {   // phase 1: pat2 rows -> LDS (coalesced float4 reads)
        const int row = t >> 3;
        const float* src = pat2 + (size_t)(kt * 32 + row) * 256 + (t & 7) * 32;
        float* dst = &spat[row][(t & 7) * 32];
        #pragma unroll
        for (int q = 0; q < 8; q++)
            *(float4*)(dst + q * 4) = *(const float4*)(src + q * 4);
    }
    __syncthreads();

    {   // phase 2: 8 interleaved dots per thread -> kvs[pattern][r]
        const int pr = t >> 3, rb = t & 7;
        const float* srow = &spat[pr][0];
        const float* wbase = wkv + (size_t)(h * 128 + z * 64 + rb) * 256;
        float acc[8] = {0.f, 0.f, 0.f, 0.f, 0.f, 0.f, 0.f, 0.f};
        for (int i4 = 0; i4 < 64; i4++) {
            const float4 x4 = *(const float4*)(srow + i4 * 4);
            #pragma unroll
            for (int i = 0; i < 8; i++) {
                const float4 w4 = *(const float4*)(wbase + (size_t)i * 8 * 256 + i4 * 4);
                acc[i] += w4.x * x4.x + w4.y * x4.y + w4.z * x4.z + w4.w * x4.w;
            }
        }
        #pragma unroll
        for (int i = 0; i < 8; i++)
            kvs[pr][rb + 8 * i] = acc[i];
    }
    __syncthreads();

    // phase 3: fragment-order gather + coalesced 16B stores
    const int lane = t & 63;
    const int cl = lane & 15, gq = lane >> 4;
    if (z == 0) {
        // K region: value = kv(pattern pl, d-col r) * 0.125*log2e
        const int f = t >> 6;
        const int pl = ((f >> 1) << 4) | cl;
        s16x8 o;
        #pragma unroll
        for (int e = 0; e < 8; e++) {
            const int c = (f & 1) * 32 + gq * 8 + e;               // permuted d col
            const int r = (c & ~0x1C) | ((c & 0x18) >> 1) | ((c & 4) << 2); // inv32^-1
            o[e] = (short)f2bf(kvs[pl][r] * KSCALE);
        }
        *(s16x8*)(k_bf + (size_t)h * 32768 + (size_t)kt * 2048 + t * 8) = o;
    } else {
        // V region: value = kv(pattern pl, 64+rd)
        const int nd = t >> 6;
        const int rd = nd * 16 + cl;
        s16x8 o;
        #pragma unroll
        for (int e = 0; e < 8; e++) {
            const int c5 = gq * 8 + e;                             // permuted pattern
            const int pl = (c5 & 3) | ((c5 & 0x18) >> 1) | ((c5 & 4) << 2); // inv32^-1
            o[e] = (short)f2bf(kvs[pl][rd]);
        }
        *(s16x8*)(v_t + (size_t)h * 32768 + (size_t)kt * 2048 + t * 8) = o;
    }
}

// ---------------------------------------------------------------- K2: conv as 3 shifted MFMA GEMMs
__global__ __launch_bounds__(256, 4)
void conv_ln_kernel(const float* __restrict__ x,
                    const short* __restrict__ wck,   // [3] frag-order [ct16][s8][512]
                    const float* __restrict__ cb,
                    short* __restrict__ xn_bf) {
    __shared__ __align__(16) short xs[66 * 268];
    const int tid = threadIdx.x;
    const int r0 = blockIdx.x * 64;
    const int pos0 = r0 & 2047;

    #pragma unroll
    for (int it = 0; it < 17; it++) {
        const int idx = tid + it * 256;              // float4 index, 4224 total
        if (idx < 4224) {
            const int row = idx >> 6, c4 = idx & 63;
            float4 v = {0.f, 0.f, 0.f, 0.f};
            if (pos0 - 2 + row >= 0)
                v = *(const float4*)(x + (size_t)(r0 - 2 + row) * 256 + c4 * 4);
            s16x4 o; o[0] = f2bf(v.x); o[1] = f2bf(v.y); o[2] = f2bf(v.z); o[3] = f2bf(v.w);
            *(s16x4*)(xs + row * 268 + c4 * 4) = o;
        }
    }
    __syncthreads();

    const int lane = tid & 63, w = tid >> 6, g = lane >> 4, cl = lane & 15;
    const int fo = lane * 8;

    f32x4 acc[4][4];
    #pragma unroll
    for (int mt = 0; mt < 4; mt++)
        #pragma unroll
        for (int nt = 0; nt < 4; nt++) acc[mt][nt] = (f32x4){0.f, 0.f, 0.f, 0.f};

    #pragma unroll
    for (int kk = 0; kk < 3; kk++) {
        const short* wb = wck + kk * 65536;
        for (int s = 0; s < 8; s++) {
            s16x8 a[4];
            #pragma unroll
            for (int mt = 0; mt < 4; mt++)
                a[mt] = *(const s16x8*)(xs + (mt * 16 + cl + kk) * 268 + s * 32 + g * 8);
            #pragma unroll
            for (int nt = 0; nt < 4; nt++) {
                const s16x8 b = *(const s16x8*)(wb + ((w * 4 + nt) * 8 + s) * 512 + fo);
                #pragma unroll
                for (int mt = 0; mt < 4; mt++)
                    acc[mt][nt] = __builtin_amdgcn_mfma_f32_16x16x32_bf16(a[mt], b, acc[mt][nt], 0, 0, 0);
            }
        }
    }

    #pragma unroll
    for (int nt = 0; nt < 4; nt++) {
        const int col = w * 64 + nt * 16 + cl;
        const float b = cb[col];
        #pragma unroll
        for (int mt = 0; mt < 4; mt++)
            #pragma unroll
            for (int r = 0; r < 4; r++) {
                const int row = mt * 16 + g * 4 + r;
                float y = acc[mt][nt][r] + b + x[(size_t)(r0 + row) * 256 + col];
                acc[mt][nt][r] = (y >= 0.f) ? y : 0.01f * y;
            }
    }
    __syncthreads();
    #pragma unroll
    for (int mt = 0; mt < 4; mt++)
        #pragma unroll
        for (int nt = 0; nt < 4; nt++)
            #pragma unroll
            for (int r = 0; r < 4; r++)
                xs[(mt * 16 + g * 4 + r) * 268 + w * 64 + nt * 16 + cl] =
                    (short)f2bf(acc[mt][nt][r]);
    __syncthreads();

    for (int q = 0; q < 16; q++) {
        const int m = w * 16 + q;
        const s16x4 v4 = *(const s16x4*)(xs + m * 268 + lane * 4);
        const float f0 = bf2f((unsigned short)v4[0]), f1 = bf2f((unsigned short)v4[1]);
        const float f2 = bf2f((unsigned short)v4[2]), f3 = bf2f((unsigned short)v4[3]);
        float s = f0 + f1 + f2 + f3;
        #pragma unroll
        for (int off = 32; off; off >>= 1) s += __shfl_xor(s, off);
        const float mu = s * (1.f / 256.f);
        const float d0 = f0 - mu, d1 = f1 - mu, d2 = f2 - mu, d3 = f3 - mu;
        float vv = d0 * d0 + d1 * d1 + d2 * d2 + d3 * d3;
        #pragma unroll
        for (int off = 32; off; off >>= 1) vv += __shfl_xor(vv, off);
        const float rs = rsqrtf(vv * (1.f / 256.f) + EPSF);
        s16x4 o; o[0] = f2bf(d0 * rs); o[1] = f2bf(d1 * rs);
        o[2] = f2bf(d2 * rs); o[3] = f2bf(d3 * rs);
        *(s16x4*)(xn_bf + (size_t)(r0 + m) * 256 + lane * 4) = o;
    }
}

// ---------------------------------------------------------------- K3: fused q-proj + attention
// Grid (T/256, 4), block 256 (4 waves, independent). Wave w owns 64 queries
// as 4 groups of 16 (u); block handles heads {2*blockIdx.y, +1}. No LDS, no
// barriers. exp2 softmax (log2e folded into K). O written in A-fragment
// order: each (u,nd) dual-store covers a dense 512B range.
__global__ __launch_bounds__(256, 2)
void qattn_kernel(const short* __restrict__ xn_bf,
                  const short* __restrict__ wq_bf,
                  const short* __restrict__ k_bf,
                  const short* __restrict__ v_t,
                  short* __restrict__ ao_bf) {
    const int tid = threadIdx.x;
    const int lane = tid & 63, w = tid >> 6, g = lane >> 4, cl = lane & 15;
    const int q0 = blockIdx.x * 256 + w * 64 + cl;   // group-0 row (+16u for u)
    const int rt0 = blockIdx.x * 16 + w * 4;         // group-0 row-tile
    const int h0 = blockIdx.y * 2;
    const int fo = lane * 8;                         // fragment lane offset (shorts)

    for (int hh = 0; hh < 2; ++hh) {
        const int h = h0 + hh;
        // ---- q-projection, 4 groups (C-layout == scores B-frag, d-permuted)
        f32x4 qacc[4][4];
        #pragma unroll
        for (int u = 0; u < 4; u++)
            #pragma unroll
            for (int nt = 0; nt < 4; nt++) qacc[u][nt] = (f32x4){0.f, 0.f, 0.f, 0.f};
        for (int s = 0; s < 8; ++s) {
            s16x8 aw[4];
            #pragma unroll
            for (int nt = 0; nt < 4; ++nt)
                aw[nt] = *(const s16x8*)(wq_bf + ((size_t)(h * 4 + nt) * 8 + s) * 512 + fo);
            #pragma unroll
            for (int u = 0; u < 4; ++u) {
                const s16x8 bx = *(const s16x8*)(xn_bf + (size_t)(q0 + 16 * u) * 256 + s * 32 + g * 8);
                #pragma unroll
                for (int nt = 0; nt < 4; ++nt)
                    qacc[u][nt] = __builtin_amdgcn_mfma_f32_16x16x32_bf16(aw[nt], bx, qacc[u][nt], 0, 0, 0);
            }
        }
        Bfrag qB[4][2];
        #pragma unroll
        for (int u = 0; u < 4; ++u)
            #pragma unroll
            for (int s = 0; s < 2; ++s) {
                qB[u][s].u[0] = pk_hi(qacc[u][2 * s][0],     qacc[u][2 * s][1]);
                qB[u][s].u[1] = pk_hi(qacc[u][2 * s][2],     qacc[u][2 * s][3]);
                qB[u][s].u[2] = pk_hi(qacc[u][2 * s + 1][0], qacc[u][2 * s + 1][1]);
                qB[u][s].u[3] = pk_hi(qacc[u][2 * s + 1][2], qacc[u][2 * s + 1][3]);
            }

        float lsum[4] = {0.f, 0.f, 0.f, 0.f};
        f32x4 oacc[4][4];
        #pragma unroll
        for (int u = 0; u < 4; u++)
            #pragma unroll
            for (int nd = 0; nd < 4; nd++) oacc[u][nd] = (f32x4){0.f, 0.f, 0.f, 0.f};

        const short* kp = k_bf + (size_t)h * 32768;
        const short* vp = v_t  + (size_t)h * 32768;

        // prologue: K frags for kt=0 (f = 0..3, each lane-linear contiguous)
        s16x8 kn0 = *(const s16x8*)(kp + fo);
        s16x8 kn1 = *(const s16x8*)(kp + fo + 512);
        s16x8 kn2 = *(const s16x8*)(kp + fo + 1024);
        s16x8 kn3 = *(const s16x8*)(kp + fo + 1536);

        for (int kt = 0; kt < 16; ++kt) {
            const s16x8 a00 = kn0, a01 = kn1, a10 = kn2, a11 = kn3;
            if (kt < 15) {                           // prefetch K frags for kt+1
                const short* kn = kp + (kt + 1) * 2048 + fo;
                kn0 = *(const s16x8*)(kn);
                kn1 = *(const s16x8*)(kn + 512);
                kn2 = *(const s16x8*)(kn + 1024);
                kn3 = *(const s16x8*)(kn + 1536);
            }
            // V frags for kt (nd = 0..3), issued before the exp chain
            const short* vb = vp + kt * 2048 + fo;
            const s16x8 va0 = *(const s16x8*)(vb);
            const s16x8 va1 = *(const s16x8*)(vb + 512);
            const s16x8 va2 = *(const s16x8*)(vb + 1024);
            const s16x8 va3 = *(const s16x8*)(vb + 1536);

            // scores S^T: rows kt*32..+32 (2 row-tiles) x 4 query groups
            f32x4 s0[4], s1[4];
            #pragma unroll
            for (int u = 0; u < 4; ++u) {
                s0[u] = (f32x4){0.f, 0.f, 0.f, 0.f};
                s1[u] = (f32x4){0.f, 0.f, 0.f, 0.f};
                s0[u] = __builtin_amdgcn_mfma_f32_16x16x32_bf16(a00, qB[u][0].s, s0[u], 0, 0, 0);
                s0[u] = __builtin_amdgcn_mfma_f32_16x16x32_bf16(a01, qB[u][1].s, s0[u], 0, 0, 0);
                s1[u] = __builtin_amdgcn_mfma_f32_16x16x32_bf16(a10, qB[u][0].s, s1[u], 0, 0, 0);
                s1[u] = __builtin_amdgcn_mfma_f32_16x16x32_bf16(a11, qB[u][1].s, s1[u], 0, 0, 0);
            }

            // softmax numerators via exp2 (K pre-scaled by 0.125*log2e)
            #pragma unroll
            for (int u = 0; u < 4; ++u)
                #pragma unroll
                for (int r = 0; r < 4; ++r) {
                    s0[u][r] = __builtin_exp2f(s0[u][r]); lsum[u] += s0[u][r];
                    s1[u][r] = __builtin_exp2f(s1[u][r]); lsum[u] += s1[u][r];
                }

            Bfrag pB[4];
            #pragma unroll
            for (int u = 0; u < 4; ++u) {
                pB[u].u[0] = pk_hi(s0[u][0], s0[u][1]);
                pB[u].u[1] = pk_hi(s0[u][2], s0[u][3]);
                pB[u].u[2] = pk_hi(s1[u][0], s1[u][1]);
                pB[u].u[3] = pk_hi(s1[u][2], s1[u][3]);
            }

            // PV: O^T += V^T-slice · P^T-slice (patterns kt*32..+32)
            #pragma unroll
            for (int u = 0; u < 4; ++u) {
                oacc[u][0] = __builtin_amdgcn_mfma_f32_16x16x32_bf16(va0, pB[u].s, oacc[u][0], 0, 0, 0);
                oacc[u][1] = __builtin_amdgcn_mfma_f32_16x16x32_bf16(va1, pB[u].s, oacc[u][1], 0, 0, 0);
                oacc[u][2] = __builtin_amdgcn_mfma_f32_16x16x32_bf16(va2, pB[u].s, oacc[u][2], 0, 0, 0);
                oacc[u][3] = __builtin_amdgcn_mfma_f32_16x16x32_bf16(va3, pB[u].s, oacc[u][3], 0, 0, 0);
            }
        }

        // normalize + write O in A-FRAGMENT order:
        // element (q=q0+16u, c=h*64+nd*16+4g+r) ->
        //   frag (rt0+u, s=h*2+(nd>>1)), offset (cl+16*((2nd+(g>>1))&3))*8+(g&1)*4
        // -> per (u,nd) the wave's dual-store covers a dense 512B range.
        #pragma unroll
        for (int u = 0; u < 4; ++u) {
            float s = lsum[u];
            s += __shfl_xor(s, 16);
            s += __shfl_xor(s, 32);
            const float inv = 1.f / s;
            #pragma unroll
            for (int nd = 0; nd < 4; ++nd) {
                const float o0 = oacc[u][nd][0] * inv, o1 = oacc[u][nd][1] * inv;
                const float o2 = oacc[u][nd][2] * inv, o3 = oacc[u][nd][3] * inv;
                const unsigned lo = (unsigned)f2bf(o0) | ((unsigned)f2bf(o1) << 16);
                const unsigned hi = (unsigned)f2bf(o2) | ((unsigned)f2bf(o3) << 16);
                short* dst = ao_bf
                    + ((size_t)(rt0 + u) * 16 + (h * 2 + (nd >> 1))) * 512
                    + (cl + 16 * ((nd * 2 + (g >> 1)) & 3)) * 8 + (g & 1) * 4;
                *(unsigned*)(dst)     = lo;
                *(unsigned*)(dst + 2) = hi;
            }
        }
    }
}

// ---------------------------------------------------------------- K4: out-proj MFMA + LN
// A-frags lane-linear DIRECT from ao frag-order (no LDS staging);
// B-frags lane-linear from wout frag-order. ys LDS only for the LN transpose.
__global__ __launch_bounds__(256, 4)
void outproj_ln_kernel(const short* __restrict__ ao,     // frag-order
                       const short* __restrict__ wout_bf, // frag-order
                       const float* __restrict__ bout,
                       float* __restrict__ out) {
    __shared__ __align__(16) float ys[32 * 260];
    const int tid = threadIdx.x;
    const int r0 = blockIdx.x * 32;
    const int lane = tid & 63, w = tid >> 6, g = lane >> 4, cl = lane & 15;
    const int fo = lane * 8;

    f32x4 acc[2][4];
    #pragma unroll
    for (int mt = 0; mt < 2; mt++)
        #pragma unroll
        for (int nt = 0; nt < 4; nt++) acc[mt][nt] = (f32x4){0.f, 0.f, 0.f, 0.f};

    const short* af = ao + (size_t)(blockIdx.x * 2) * 16 * 512;   // row-tile rt0

    for (int s = 0; s < 16; s++) {
        const s16x8 a0 = *(const s16x8*)(af + (size_t)s * 512 + fo);
        const s16x8 a1 = *(const s16x8*)(af + (size_t)(16 + s) * 512 + fo);
        #pragma unroll
        for (int nt = 0; nt < 4; nt++) {
            const s16x8 b = *(const s16x8*)(wout_bf + (size_t)((w * 4 + nt) * 16 + s) * 512 + fo);
            acc[0][nt] = __builtin_amdgcn_mfma_f32_16x16x32_bf16(a0, b, acc[0][nt], 0, 0, 0);
            acc[1][nt] = __builtin_amdgcn_mfma_f32_16x16x32_bf16(a1, b, acc[1][nt], 0, 0, 0);
        }
    }
    __syncthreads();

    #pragma unroll
    for (int nt = 0; nt < 4; nt++) {
        const int col = w * 64 + nt * 16 + cl;
        const float b = bout[col];
        #pragma unroll
        for (int mt = 0; mt < 2; mt++)
            #pragma unroll
            for (int r = 0; r < 4; r++)
                ys[(mt * 16 + g * 4 + r) * 260 + col] = acc[mt][nt][r] + b;
    }
    __syncthreads();

    for (int q = 0; q < 8; q++) {
        const int m = w * 8 + q;
        const float4 v4 = *(const float4*)(ys + m * 260 + lane * 4);
        float s = v4.x + v4.y + v4.z + v4.w;
        #pragma unroll
        for (int off = 32; off; off >>= 1) s += __shfl_xor(s, off);
        const float mu = s * (1.f / 256.f);
        const float d0 = v4.x - mu, d1 = v4.y - mu, d2 = v4.z - mu, d3 = v4.w - mu;
        float vv = d0 * d0 + d1 * d1 + d2 * d2 + d3 * d3;
        #pragma unroll
        for (int off = 32; off; off >>= 1) vv += __shfl_xor(vv, off);
        const float rs = rsqrtf(vv * (1.f / 256.f) + EPSF);
        float4 o; o.x = d0 * rs; o.y = d1 * rs; o.z = d2 * rs; o.w = d3 * rs;
        *(float4*)(out + (size_t)(r0 + m) * 256 + lane * 4) = o;
    }
}

// ---------------------------------------------------------------- launch
extern "C" void kernel_launch(void* const* d_in, const int* in_sizes, int n_in,
                              void* d_out, int out_size, void* d_ws, size_t ws_size,
                              hipStream_t stream) {
    const float* normed_x = (const float*)d_in[0];
    const float* conv_w   = (const float*)d_in[1];
    const float* conv_b   = (const float*)d_in[2];
    const float* pattern  = (const float*)d_in[3];
    const float* wq       = (const float*)d_in[4];
    const float* wkv      = (const float*)d_in[5];
    const float* wout     = (const float*)d_in[6];
    const float* bout     = (const float*)d_in[7];
    const int T = in_sizes[0] / 256;               // 65536

    char* wsb = (char*)d_ws;
    short* xn_bf  = (short*)(wsb);                             // T*256 bf16 = 32 MB
    short* ao_bf  = (short*)(wsb + (size_t)33554432);          // T*512 bf16 = 64 MB
    short* k_bf   = (short*)(wsb + (size_t)100663296);         // 512 KB
    short* v_t    = (short*)(wsb + (size_t)101187584);         // 512 KB
    short* wq_bf  = (short*)(wsb + (size_t)101711872);         // 256 KB
    short* wout_bf= (short*)(wsb + (size_t)101974016);         // 256 KB
    short* wck    = (short*)(wsb + (size_t)102236160);         // 384 KB
    // pat2 aliases the head of ao_bf: pat2 is dead before qattn writes ao_bf.
    float* pat2   = (float*)(wsb + (size_t)33554432);          // 512 KB (alias)
    float* out    = (float*)d_out;

    cvt_kernel<<<512, 256, 0, stream>>>(wq, wout, conv_w, wq_bf, wout_bf, wck);
    pat_ln_kernel<<<512, 256, 0, stream>>>(pattern, pat2);
    kv_frag_kernel<<<dim3(16, 8, 2), 256, 0, stream>>>(pat2, wkv, k_bf, v_t);
    conv_ln_kernel<<<T / 64, 256, 0, stream>>>(normed_x, wck, conv_b, xn_bf);
    qattn_kernel<<<dim3(T / 256, 4), 256, 0, stream>>>(xn_bf, wq_bf, k_bf, v_t, ao_bf);
    outproj_ln_kernel<<<T / 32, 256, 0, stream>>>(ao_bf, wout_bf, bout, out);
}